// Round 5
// baseline (465.734 us; speedup 1.0000x reference)
//
#include <hip/hip_runtime.h>
#include <hip/hip_bf16.h>

#define N 8192
#define FIN 512
#define FOUT 64
#define ALPHA 0.2f

typedef __bf16 bf16x8 __attribute__((ext_vector_type(8)));
typedef __bf16 bf16x4 __attribute__((ext_vector_type(4)));
typedef float f32x4 __attribute__((ext_vector_type(4)));
typedef int i32x4 __attribute__((ext_vector_type(4)));

constexpr int JCH = 256;      // j-chunk staged per barrier
constexpr int CPB = 4;        // chunks per block (block j-span = 1024)
constexpr int NCH = 8;        // grid.y partial-sum slices
constexpr int HSTR = JCH + 8; // 264: LDS stride for hT tile & w tiles

// ---- workspace layout (bytes) ----
// 0        : Mkey (ordered-uint global max of f_dst; memset 0)
// 4096     : f_src (32 KB)
// 36864    : f_dst (32 KB)
// 69632    : WtG (bf16 [FOUT][FIN], 64 KB)
// 135168   : hT  (bf16 [FOUT][N], 1 MB)
// 2097152  : plsum (NCH x N f32, 256 KB)
// 4194304  : pnum  (NCH x N x FOUT f32, 16 MB)

__device__ __forceinline__ unsigned enc_f(float x) {
    unsigned u = __float_as_uint(x);
    return (u & 0x80000000u) ? ~u : (u | 0x80000000u);
}
__device__ __forceinline__ float dec_f(unsigned u) {
    return (u & 0x80000000u) ? __uint_as_float(u & 0x7FFFFFFFu) : __uint_as_float(~u);
}

// ---------- k_wt: WtG[f][k] = bf16(W[k][f]) --------------------------------
__global__ __launch_bounds__(64) void k_wt(const float* __restrict__ W,
                                           __bf16* __restrict__ WtG) {
    const int g = blockIdx.x * 64 + threadIdx.x;  // 0..4095
    const int k = g >> 3;
    const int f0 = (g & 7) * 8;
    const float4 w0 = *(const float4*)(W + (size_t)k * FOUT + f0);
    const float4 w1 = *(const float4*)(W + (size_t)k * FOUT + f0 + 4);
    WtG[(size_t)(f0 + 0) * FIN + k] = (__bf16)w0.x;
    WtG[(size_t)(f0 + 1) * FIN + k] = (__bf16)w0.y;
    WtG[(size_t)(f0 + 2) * FIN + k] = (__bf16)w0.z;
    WtG[(size_t)(f0 + 3) * FIN + k] = (__bf16)w0.w;
    WtG[(size_t)(f0 + 4) * FIN + k] = (__bf16)w1.x;
    WtG[(size_t)(f0 + 5) * FIN + k] = (__bf16)w1.y;
    WtG[(size_t)(f0 + 6) * FIN + k] = (__bf16)w1.z;
    WtG[(size_t)(f0 + 7) * FIN + k] = (__bf16)w1.w;
}

// ---------- k12: h=in@W (MFMA) -> f_src/f_dst/Mkey + hT (fused) ------------
__global__ __launch_bounds__(64) void k12(const float* __restrict__ in,
                                          const __bf16* __restrict__ WtG,
                                          const float* __restrict__ a,
                                          float* __restrict__ f_src,
                                          float* __restrict__ f_dst,
                                          unsigned* __restrict__ Mkey,
                                          __bf16* __restrict__ hT) {
    __shared__ __bf16 tb[64][16];
    const int lane = threadIdx.x;
    const int m = lane & 15, quad = lane >> 4;
    const int i0 = blockIdx.x * 16;

    f32x4 acc[4];
#pragma unroll
    for (int t = 0; t < 4; ++t) acc[t] = (f32x4){0.f, 0.f, 0.f, 0.f};

    const float* arow = in + (size_t)(i0 + m) * FIN + quad * 8;
    for (int k0 = 0; k0 < FIN; k0 += 32) {
        const float4 x0 = *(const float4*)(arow + k0);
        const float4 x1 = *(const float4*)(arow + k0 + 4);
        bf16x8 af;
        af[0] = (__bf16)x0.x; af[1] = (__bf16)x0.y; af[2] = (__bf16)x0.z; af[3] = (__bf16)x0.w;
        af[4] = (__bf16)x1.x; af[5] = (__bf16)x1.y; af[6] = (__bf16)x1.z; af[7] = (__bf16)x1.w;
#pragma unroll
        for (int t = 0; t < 4; ++t) {
            const bf16x8 bf = *(const bf16x8*)(WtG + (size_t)(t * 16 + m) * FIN + k0 + quad * 8);
            acc[t] = __builtin_amdgcn_mfma_f32_16x16x32_bf16(af, bf, acc[t], 0, 0, 0);
        }
    }
    float s1[4], s2[4];
#pragma unroll
    for (int r = 0; r < 4; ++r) { s1[r] = 0.f; s2[r] = 0.f; }
#pragma unroll
    for (int t = 0; t < 4; ++t) {
        const float a1 = a[t * 16 + m], a2 = a[64 + t * 16 + m];
#pragma unroll
        for (int r = 0; r < 4; ++r) {
            s1[r] += acc[t][r] * a1;
            s2[r] += acc[t][r] * a2;
        }
    }
#pragma unroll
    for (int off = 1; off <= 8; off <<= 1)
#pragma unroll
        for (int r = 0; r < 4; ++r) {
            s1[r] += __shfl_xor(s1[r], off);
            s2[r] += __shfl_xor(s2[r], off);
        }
    float lm = -1e30f;
    if (m == 0) {
#pragma unroll
        for (int r = 0; r < 4; ++r) {
            f_src[i0 + quad * 4 + r] = s1[r];
            f_dst[i0 + quad * 4 + r] = s2[r];
            lm = fmaxf(lm, s2[r]);
        }
    }
    lm = fmaxf(lm, __shfl_xor(lm, 16));
    lm = fmaxf(lm, __shfl_xor(lm, 32));
    if (lane == 0) atomicMax(Mkey, enc_f(lm));

#pragma unroll
    for (int t = 0; t < 4; ++t)
#pragma unroll
        for (int r = 0; r < 4; ++r) tb[t * 16 + m][quad * 4 + r] = (__bf16)acc[t][r];
    __syncthreads();
    {
        const int f = lane;
        const bf16x8 v0 = *(const bf16x8*)&tb[f][0];
        const bf16x8 v1 = *(const bf16x8*)&tb[f][8];
        *(bf16x8*)(hT + (size_t)f * N + i0) = v0;
        *(bf16x8*)(hT + (size_t)f * N + i0 + 8) = v1;
    }
}

// ---------- k3: fused mask+softmax-weight+PV -------------------------------
// KEY CHANGE vs R4: adj is read CONTIGUOUSLY — each load instr covers 1 KB of
// ONE row (lane l -> cols l*4..l*4+3), instead of 16 rows x 64 B. fs/shift
// become wave-uniform scalars. Weights are computed in that layout and
// transposed to MFMA A-fragment layout via wave-private LDS tiles.
__global__ __launch_bounds__(256) void k3_attn(const int* __restrict__ adj,
                                               const float* __restrict__ f_src,
                                               const float* __restrict__ fdstG,
                                               const unsigned* __restrict__ Mkey,
                                               const __bf16* __restrict__ hT,
                                               float* __restrict__ pnum,
                                               float* __restrict__ plsum) {
    __shared__ __bf16 sh[64 * HSTR];       // hT tile, 33,792 B
    __shared__ __bf16 wlds[4 * 16 * HSTR]; // per-wave weight tiles, 33,792 B
    const int tid = threadIdx.x;
    const int wv = tid >> 6, lane = tid & 63;
    const int m = lane & 15, quad = lane >> 4;
    const int i0w = (blockIdx.x * 4 + wv) * 16;  // this wave's 16 rows
    const int jb = blockIdx.y * (JCH * CPB);
    const float LOG2E = 1.44269504088896f;
    const int wbase = wv * 16 * HSTR;

    const float M = dec_f(*Mkey);
    // wave-uniform per-row softmax params (SGPR-resident under unroll)
    float fsr_a[16], shr_a[16];
#pragma unroll
    for (int r = 0; r < 16; ++r) {
        const float fsr = f_src[i0w + r];
        const float tt = fsr + M;
        fsr_a[r] = fsr;
        shr_a[r] = fmaxf(tt, ALPHA * tt);  // leaky(fs + max f_dst) >= every e
    }

    f32x4 acc[4];
#pragma unroll
    for (int t = 0; t < 4; ++t) acc[t] = (f32x4){0.f, 0.f, 0.f, 0.f};
    f32x4 accl = (f32x4){0.f, 0.f, 0.f, 0.f};

    bf16x8 bones;  // ones-column B: row-sums -> denominator
#pragma unroll
    for (int jj = 0; jj < 8; ++jj) bones[jj] = (__bf16)(m == 0 ? 1.0f : 0.0f);

    for (int c = 0; c < CPB; ++c) {
        const int jc = jb + c * JCH;
        __syncthreads();  // protect sh/wlds reuse from previous chunk's reads

        // cooperative hT tile staging: 64 f-rows x 256 cols (32 KB, L2-hit)
#pragma unroll
        for (int k = 0; k < 8; ++k) {
            const int s = tid + k * 256;       // 2048 slots of bf16x8
            const int f = s >> 5, off = (s & 31) * 8;
            *(bf16x8*)&sh[f * HSTR + off] = *(const bf16x8*)(hT + (size_t)f * N + jc + off);
        }

        // per-wave: contiguous adj row loads + weight gen into wlds
        const f32x4 fd = *(const f32x4*)(fdstG + jc + lane * 4);
#pragma unroll
        for (int r = 0; r < 16; ++r) {
            const i32x4 am = __builtin_nontemporal_load(
                (const i32x4*)(adj + (size_t)(i0w + r) * N + jc + lane * 4));
            const float fsr = fsr_a[r], sh_r = shr_a[r];
            bf16x4 w4;
#pragma unroll
            for (int jj = 0; jj < 4; ++jj) {
                float e = fsr + fd[jj];
                e = fmaxf(e, ALPHA * e);
                const float ex = __builtin_amdgcn_exp2f((e - sh_r) * LOG2E);
                w4[jj] = (__bf16)(am[jj] > 0 ? ex : 0.f);
            }
            *(bf16x4*)&wlds[wbase + r * HSTR + lane * 4] = w4;
        }
        __syncthreads();  // sh + wlds visible

        // MFMA over the 256-j chunk (K = 256 -> 8 k-steps)
#pragma unroll
        for (int s = 0; s < 8; ++s) {
            const bf16x8 af = *(const bf16x8*)&wlds[wbase + m * HSTR + s * 32 + quad * 8];
#pragma unroll
            for (int t = 0; t < 4; ++t) {
                const bf16x8 bfr = *(const bf16x8*)&sh[(t * 16 + m) * HSTR + s * 32 + quad * 8];
                acc[t] = __builtin_amdgcn_mfma_f32_16x16x32_bf16(af, bfr, acc[t], 0, 0, 0);
            }
            accl = __builtin_amdgcn_mfma_f32_16x16x32_bf16(af, bones, accl, 0, 0, 0);
        }
    }

    // disjoint partial-sum stores (C/D: col=lane&15, row=quad*4+reg)
    float* pn = pnum + (size_t)blockIdx.y * N * FOUT;
#pragma unroll
    for (int t = 0; t < 4; ++t)
#pragma unroll
        for (int r = 0; r < 4; ++r)
            pn[(size_t)(i0w + quad * 4 + r) * FOUT + t * 16 + m] = acc[t][r];
    if (m == 0) {
#pragma unroll
        for (int r = 0; r < 4; ++r)
            plsum[(size_t)blockIdx.y * N + i0w + quad * 4 + r] = accl[r];
    }
}

// ---------- k4: reduce partials, out = leaky(num/lsum, 0.01) ---------------
__global__ __launch_bounds__(256) void k4_norm(const float* __restrict__ pnum,
                                               const float* __restrict__ plsum,
                                               float* __restrict__ out) {
    const int idx = blockIdx.x * 256 + threadIdx.x;  // over N*FOUT
    const int row = idx >> 6;
    float s = 0.f, l = 0.f;
#pragma unroll
    for (int c = 0; c < NCH; ++c) {
        s += pnum[(size_t)c * N * FOUT + idx];
        l += plsum[(size_t)c * N + row];
    }
    const float v = s / (l > 0.f ? l : 1.f);
    out[idx] = v > 0.f ? v : 0.01f * v;
}

extern "C" void kernel_launch(void* const* d_in, const int* in_sizes, int n_in,
                              void* d_out, int out_size, void* d_ws, size_t ws_size,
                              hipStream_t stream) {
    const float* in = (const float*)d_in[0];
    const int* adj = (const int*)d_in[1];
    const float* W = (const float*)d_in[2];
    const float* a = (const float*)d_in[3];
    float* out = (float*)d_out;

    char* ws = (char*)d_ws;
    unsigned* Mkey = (unsigned*)ws;
    float* f_src = (float*)(ws + 4096);
    float* f_dst = (float*)(ws + 36864);
    __bf16* WtG = (__bf16*)(ws + 69632);
    __bf16* hT = (__bf16*)(ws + 135168);
    float* plsum = (float*)(ws + 2097152);
    float* pnum = (float*)(ws + 4194304);

    hipMemsetAsync(ws, 0, 64, stream);  // Mkey only

    k_wt<<<64, 64, 0, stream>>>(W, WtG);
    k12<<<N / 16, 64, 0, stream>>>(in, WtG, a, f_src, f_dst, Mkey, hT);

    dim3 g3(N / 64, NCH);
    k3_attn<<<g3, 256, 0, stream>>>(adj, f_src, f_dst, Mkey, hT, pnum, plsum);
    k4_norm<<<(N * FOUT) / 256, 256, 0, stream>>>(pnum, plsum, out);
}

// Round 6
// 442.114 us; speedup vs baseline: 1.0534x; 1.0534x over previous
//
#include <hip/hip_runtime.h>
#include <hip/hip_bf16.h>

#define N 8192
#define FIN 512
#define FOUT 64
#define ALPHA 0.2f

typedef __bf16 bf16x8 __attribute__((ext_vector_type(8)));
typedef float f32x4 __attribute__((ext_vector_type(4)));
typedef int i32x4 __attribute__((ext_vector_type(4)));

constexpr int JCH = 256;       // j-chunk staged per barrier
constexpr int CPB = 2;         // chunks per block (block j-span = 512)
constexpr int NCH = 16;        // grid.y partial-sum slices
constexpr int HSTR = JCH + 8;  // 264: LDS stride (odd in 16B units -> swizzled)
constexpr int NW = N / 32;     // 256 bitmask words per row

// ---- workspace layout (bytes) ----
// 0        : Mkey (ordered-uint global max of f_dst; memset 0)
// 4096     : f_src (32 KB)
// 36864    : f_dst (32 KB)
// 69632    : WtG (bf16 [FOUT][FIN], 64 KB)
// 135168   : hT  (bf16 [FOUT][N], 1 MB)
// 1183744  : abit (u32 [N][NW], 8 MB)
// 16777216 : plsum (NCH x N f32, 512 KB)
// 20971520 : pnum  (NCH x N x FOUT f32, 32 MB)

__device__ __forceinline__ unsigned enc_f(float x) {
    unsigned u = __float_as_uint(x);
    return (u & 0x80000000u) ? ~u : (u | 0x80000000u);
}
__device__ __forceinline__ float dec_f(unsigned u) {
    return (u & 0x80000000u) ? __uint_as_float(u & 0x7FFFFFFFu) : __uint_as_float(~u);
}

// ---------- k_wt: WtG[f][k] = bf16(W[k][f]) --------------------------------
__global__ __launch_bounds__(64) void k_wt(const float* __restrict__ W,
                                           __bf16* __restrict__ WtG) {
    const int g = blockIdx.x * 64 + threadIdx.x;  // 0..4095
    const int k = g >> 3;
    const int f0 = (g & 7) * 8;
    const float4 w0 = *(const float4*)(W + (size_t)k * FOUT + f0);
    const float4 w1 = *(const float4*)(W + (size_t)k * FOUT + f0 + 4);
    WtG[(size_t)(f0 + 0) * FIN + k] = (__bf16)w0.x;
    WtG[(size_t)(f0 + 1) * FIN + k] = (__bf16)w0.y;
    WtG[(size_t)(f0 + 2) * FIN + k] = (__bf16)w0.z;
    WtG[(size_t)(f0 + 3) * FIN + k] = (__bf16)w0.w;
    WtG[(size_t)(f0 + 4) * FIN + k] = (__bf16)w1.x;
    WtG[(size_t)(f0 + 5) * FIN + k] = (__bf16)w1.y;
    WtG[(size_t)(f0 + 6) * FIN + k] = (__bf16)w1.z;
    WtG[(size_t)(f0 + 7) * FIN + k] = (__bf16)w1.w;
}

// ---------- k_pack: abit[i][j/32] bit j%32 = (adj[i][j] > 0) ---------------
// Pure streaming shape: contiguous i32x4 reads, tiny writes, no barriers.
__global__ __launch_bounds__(256) void k_pack(const int* __restrict__ adj,
                                              unsigned* __restrict__ abit) {
    const int lane = threadIdx.x & 63;
    const int wg = blockIdx.x * 4 + (threadIdx.x >> 6);  // 0..4095
#pragma unroll
    for (int rr = 0; rr < 2; ++rr) {
        const int row = wg * 2 + rr;
        const int* src = adj + (size_t)row * N;
        unsigned* dst = abit + (size_t)row * NW;
#pragma unroll 4
        for (int c = 0; c < 32; ++c) {
            const i32x4 v = *(const i32x4*)(src + c * 256 + lane * 4);
            unsigned w = ((unsigned)(v[0] > 0) | ((unsigned)(v[1] > 0) << 1) |
                          ((unsigned)(v[2] > 0) << 2) | ((unsigned)(v[3] > 0) << 3))
                         << (4 * (lane & 7));
            w |= __shfl_xor(w, 1);
            w |= __shfl_xor(w, 2);
            w |= __shfl_xor(w, 4);
            if ((lane & 7) == 0) dst[c * 8 + (lane >> 3)] = w;
        }
    }
}

// ---------- k12: h=in@W (MFMA) -> f_src/f_dst/Mkey + hT (fused) ------------
__global__ __launch_bounds__(64) void k12(const float* __restrict__ in,
                                          const __bf16* __restrict__ WtG,
                                          const float* __restrict__ a,
                                          float* __restrict__ f_src,
                                          float* __restrict__ f_dst,
                                          unsigned* __restrict__ Mkey,
                                          __bf16* __restrict__ hT) {
    __shared__ __bf16 tb[64][16];
    const int lane = threadIdx.x;
    const int m = lane & 15, quad = lane >> 4;
    const int i0 = blockIdx.x * 16;

    f32x4 acc[4];
#pragma unroll
    for (int t = 0; t < 4; ++t) acc[t] = (f32x4){0.f, 0.f, 0.f, 0.f};

    const float* arow = in + (size_t)(i0 + m) * FIN + quad * 8;
    for (int k0 = 0; k0 < FIN; k0 += 32) {
        const float4 x0 = *(const float4*)(arow + k0);
        const float4 x1 = *(const float4*)(arow + k0 + 4);
        bf16x8 af;
        af[0] = (__bf16)x0.x; af[1] = (__bf16)x0.y; af[2] = (__bf16)x0.z; af[3] = (__bf16)x0.w;
        af[4] = (__bf16)x1.x; af[5] = (__bf16)x1.y; af[6] = (__bf16)x1.z; af[7] = (__bf16)x1.w;
#pragma unroll
        for (int t = 0; t < 4; ++t) {
            const bf16x8 bf = *(const bf16x8*)(WtG + (size_t)(t * 16 + m) * FIN + k0 + quad * 8);
            acc[t] = __builtin_amdgcn_mfma_f32_16x16x32_bf16(af, bf, acc[t], 0, 0, 0);
        }
    }
    float s1[4], s2[4];
#pragma unroll
    for (int r = 0; r < 4; ++r) { s1[r] = 0.f; s2[r] = 0.f; }
#pragma unroll
    for (int t = 0; t < 4; ++t) {
        const float a1 = a[t * 16 + m], a2 = a[64 + t * 16 + m];
#pragma unroll
        for (int r = 0; r < 4; ++r) {
            s1[r] += acc[t][r] * a1;
            s2[r] += acc[t][r] * a2;
        }
    }
#pragma unroll
    for (int off = 1; off <= 8; off <<= 1)
#pragma unroll
        for (int r = 0; r < 4; ++r) {
            s1[r] += __shfl_xor(s1[r], off);
            s2[r] += __shfl_xor(s2[r], off);
        }
    float lm = -1e30f;
    if (m == 0) {
#pragma unroll
        for (int r = 0; r < 4; ++r) {
            f_src[i0 + quad * 4 + r] = s1[r];
            f_dst[i0 + quad * 4 + r] = s2[r];
            lm = fmaxf(lm, s2[r]);
        }
    }
    lm = fmaxf(lm, __shfl_xor(lm, 16));
    lm = fmaxf(lm, __shfl_xor(lm, 32));
    if (lane == 0) atomicMax(Mkey, enc_f(lm));

#pragma unroll
    for (int t = 0; t < 4; ++t)
#pragma unroll
        for (int r = 0; r < 4; ++r) tb[t * 16 + m][quad * 4 + r] = (__bf16)acc[t][r];
    __syncthreads();
    {
        const int f = lane;
        const bf16x8 v0 = *(const bf16x8*)&tb[f][0];
        const bf16x8 v1 = *(const bf16x8*)&tb[f][8];
        *(bf16x8*)(hT + (size_t)f * N + i0) = v0;
        *(bf16x8*)(hT + (size_t)f * N + i0 + 8) = v1;
    }
}

// ---------- k3: bitmask -> softmax weights (in A-frag layout) -> PV --------
// No adj HBM stream. Each wave covers 64 rows (4 A-tiles) so the LDS-staged
// hT B-fragments are reused 4x. Weights generated directly in A-fragment
// layout: lane(m,quad) owns row m, j = quad*8+jj -> bit quad*8+jj of
// abit[row][j/32]. Denominator via ones-column MFMA.
__global__ __launch_bounds__(256) void k3_attn(const unsigned* __restrict__ abit,
                                               const float* __restrict__ f_src,
                                               const float* __restrict__ fdstG,
                                               const unsigned* __restrict__ Mkey,
                                               const __bf16* __restrict__ hT,
                                               float* __restrict__ pnum,
                                               float* __restrict__ plsum) {
    __shared__ __bf16 sh[64 * HSTR];  // hT tile, 33,792 B
    __shared__ float sfd[JCH * CPB];  // 2 KB
    const int tid = threadIdx.x;
    const int wv = tid >> 6, lane = tid & 63;
    const int m = lane & 15, quad = lane >> 4;
    const int i0w = blockIdx.x * 256 + wv * 64;  // wave's 64 rows
    const int jb = blockIdx.y * (JCH * CPB);
    const float LOG2E = 1.44269504088896f;

    // stage f_dst slice once (512 floats)
    if (tid < (JCH * CPB) / 4) *(f32x4*)&sfd[tid * 4] = *(const f32x4*)(fdstG + jb + tid * 4);

    const float M = dec_f(*Mkey);
    float fs[4], sht[4];
#pragma unroll
    for (int mt = 0; mt < 4; ++mt) {
        fs[mt] = f_src[i0w + mt * 16 + m];
        const float tt = fs[mt] + M;
        sht[mt] = fmaxf(tt, ALPHA * tt);  // leaky(fs + max f_dst) >= every e
    }

    f32x4 acc[4][4], accl[4];
#pragma unroll
    for (int mt = 0; mt < 4; ++mt) {
        accl[mt] = (f32x4){0.f, 0.f, 0.f, 0.f};
#pragma unroll
        for (int t = 0; t < 4; ++t) acc[mt][t] = (f32x4){0.f, 0.f, 0.f, 0.f};
    }

    bf16x8 bones;  // ones-column B -> row sums (denominator)
#pragma unroll
    for (int jj = 0; jj < 8; ++jj) bones[jj] = (__bf16)(m == 0 ? 1.0f : 0.0f);

    for (int c = 0; c < CPB; ++c) {
        const int jc = jb + c * JCH;
        __syncthreads();  // protect sh reuse
        // cooperative hT tile staging: 64 f-rows x 256 cols (32 KB, L2-hot)
#pragma unroll
        for (int k = 0; k < 8; ++k) {
            const int s = tid + k * 256;  // 2048 bf16x8 slots
            const int f = s >> 5, off = (s & 31) * 8;
            *(bf16x8*)&sh[f * HSTR + off] = *(const bf16x8*)(hT + (size_t)f * N + jc + off);
        }
        __syncthreads();

#pragma unroll
        for (int s = 0; s < 8; ++s) {
            const int widx = (jc >> 5) + s;
            const f32x4 fd0 = *(const f32x4*)&sfd[c * JCH + s * 32 + quad * 8];
            const f32x4 fd1 = *(const f32x4*)&sfd[c * JCH + s * 32 + quad * 8 + 4];
            bf16x8 B[4];
#pragma unroll
            for (int t = 0; t < 4; ++t)
                B[t] = *(const bf16x8*)&sh[(t * 16 + m) * HSTR + s * 32 + quad * 8];
#pragma unroll
            for (int mt = 0; mt < 4; ++mt) {
                const unsigned mw = abit[(size_t)(i0w + mt * 16 + m) * NW + widx];
                const unsigned bits = mw >> (quad * 8);
                bf16x8 af;
#pragma unroll
                for (int jj = 0; jj < 8; ++jj) {
                    float e = fs[mt] + (jj < 4 ? fd0[jj] : fd1[jj - 4]);
                    e = fmaxf(e, ALPHA * e);
                    const float ex = __builtin_amdgcn_exp2f((e - sht[mt]) * LOG2E);
                    af[jj] = (__bf16)(((bits >> jj) & 1u) ? ex : 0.f);
                }
#pragma unroll
                for (int t = 0; t < 4; ++t)
                    acc[mt][t] = __builtin_amdgcn_mfma_f32_16x16x32_bf16(af, B[t], acc[mt][t], 0, 0, 0);
                accl[mt] = __builtin_amdgcn_mfma_f32_16x16x32_bf16(af, bones, accl[mt], 0, 0, 0);
            }
        }
    }

    // disjoint partial-sum stores (C/D: col=lane&15, row=quad*4+reg)
    float* pn = pnum + (size_t)blockIdx.y * N * FOUT;
#pragma unroll
    for (int mt = 0; mt < 4; ++mt) {
#pragma unroll
        for (int t = 0; t < 4; ++t)
#pragma unroll
            for (int r = 0; r < 4; ++r)
                pn[(size_t)(i0w + mt * 16 + quad * 4 + r) * FOUT + t * 16 + m] = acc[mt][t][r];
        if (m == 0) {
#pragma unroll
            for (int r = 0; r < 4; ++r)
                plsum[(size_t)blockIdx.y * N + i0w + mt * 16 + quad * 4 + r] = accl[mt][r];
        }
    }
}

// ---------- k4: reduce partials, out = leaky(num/lsum, 0.01) ---------------
__global__ __launch_bounds__(256) void k4_norm(const float* __restrict__ pnum,
                                               const float* __restrict__ plsum,
                                               float* __restrict__ out) {
    const int idx = blockIdx.x * 256 + threadIdx.x;  // over N*FOUT
    const int row = idx >> 6;
    float s = 0.f, l = 0.f;
#pragma unroll
    for (int c = 0; c < NCH; ++c) {
        s += pnum[(size_t)c * N * FOUT + idx];
        l += plsum[(size_t)c * N + row];
    }
    const float v = s / (l > 0.f ? l : 1.f);
    out[idx] = v > 0.f ? v : 0.01f * v;
}

extern "C" void kernel_launch(void* const* d_in, const int* in_sizes, int n_in,
                              void* d_out, int out_size, void* d_ws, size_t ws_size,
                              hipStream_t stream) {
    const float* in = (const float*)d_in[0];
    const int* adj = (const int*)d_in[1];
    const float* W = (const float*)d_in[2];
    const float* a = (const float*)d_in[3];
    float* out = (float*)d_out;

    char* ws = (char*)d_ws;
    unsigned* Mkey = (unsigned*)ws;
    float* f_src = (float*)(ws + 4096);
    float* f_dst = (float*)(ws + 36864);
    __bf16* WtG = (__bf16*)(ws + 69632);
    __bf16* hT = (__bf16*)(ws + 135168);
    unsigned* abit = (unsigned*)(ws + 1183744);
    float* plsum = (float*)(ws + 16777216);
    float* pnum = (float*)(ws + 20971520);

    hipMemsetAsync(ws, 0, 64, stream);  // Mkey only

    k_wt<<<64, 64, 0, stream>>>(W, WtG);
    k_pack<<<1024, 256, 0, stream>>>(adj, abit);
    k12<<<N / 16, 64, 0, stream>>>(in, WtG, a, f_src, f_dst, Mkey, hT);

    dim3 g3(N / 256, NCH);
    k3_attn<<<g3, 256, 0, stream>>>(abit, f_src, f_dst, Mkey, hT, pnum, plsum);
    k4_norm<<<(N * FOUT) / 256, 256, 0, stream>>>(pnum, plsum, out);
}